// Round 3
// baseline (4760.382 us; speedup 1.0000x reference)
//
#include <hip/hip_runtime.h>
#include <math.h>

#define EPSV 1e-5f

typedef unsigned short ushort_t;
typedef __attribute__((ext_vector_type(8))) short bf16x8;
typedef __attribute__((ext_vector_type(8))) unsigned short u16x8;
typedef __attribute__((ext_vector_type(4))) float f32x4;

#define N_P  31719424   // 64*256*44*44 elements of p
#define N_CW 589824     // 256*256*9 conv weights
#define N_QW 131072     // 512*256 qkv weights (per axial)

// split-bf16 weights, fragment-ordered (rewritten every launch)
__device__ __align__(16) ushort_t g_cwhi[N_CW];
__device__ __align__(16) ushort_t g_cwlo[N_CW];
__device__ __align__(16) ushort_t g_qwhi[2][N_QW];
__device__ __align__(16) ushort_t g_qwlo[2][N_QW];

__device__ __forceinline__ ushort_t f2bf_rn(float f) {
    unsigned int u = __float_as_uint(f);
    unsigned int r = u + 0x7FFFu + ((u >> 16) & 1u);
    return (ushort_t)(r >> 16);
}
__device__ __forceinline__ float bf2f(ushort_t h) {
    return __uint_as_float(((unsigned int)h) << 16);
}
// swizzled byte offset for 192B-stride rows (quad-spread float4 columns)
__device__ __forceinline__ unsigned swz192(int r, int byteoff) {
    return ((unsigned)(r * 192 + byteoff)) ^ (((unsigned)(r & 7)) << 4);
}

// ---------------------------------------------------------------------------
// conv weight split (fragment order), as validated in round 2
// ---------------------------------------------------------------------------
__global__ __launch_bounds__(256)
void wsplit_conv(const float* __restrict__ cw)
{
    int idx = blockIdx.x * 256 + threadIdx.x;
    if (idx >= N_CW) return;
    int tap = idx % 9;
    int rem = idx / 9;
    int ci = rem & 255, co = rem >> 8;
    float w = cw[idx];
    ushort_t hi = f2bf_rn(w);
    ushort_t lo = f2bf_rn(w - bf2f(hi));
    int cit = ci >> 5, ci5 = ci & 31, ci8 = ci5 >> 3, e = ci5 & 7;
    int didx = (((cit * 9 + tap) * 4 + ci8) * 256 + co) * 8 + e;
    g_cwhi[didx] = hi;
    g_cwlo[didx] = lo;
}

// qkv weight split: [kt][ci8][o=512][e=8] fragment order, both axials
__global__ __launch_bounds__(256)
void wsplit_qkv(const float* __restrict__ wh_, const float* __restrict__ ww_)
{
    int idx = blockIdx.x * 256 + threadIdx.x;
    if (idx >= 2 * N_QW) return;
    int sel = idx >> 17;
    int id  = idx & (N_QW - 1);
    float w = (sel ? ww_ : wh_)[id];
    ushort_t hi = f2bf_rn(w);
    ushort_t lo = f2bf_rn(w - bf2f(hi));
    int o = id >> 8, c = id & 255;
    int kt = c >> 5, ci8 = (c >> 3) & 3, e = c & 7;
    int didx = ((kt * 4 + ci8) * 512 + o) * 8 + e;
    g_qwhi[sel][didx] = hi;
    g_qwlo[sel][didx] = lo;
}

// ---------------------------------------------------------------------------
// Axial attention megakernel, MFMA qkv. One block per column (n,col), 256 thr.
// LDS union (49152 B, 3 blocks/CU):
//   phase 1: Xhi[48][256]@0 (24576) + Xlo@24576 (24576), XOR-swizzled 16B slots
//   phase 2: qb[128 rows,192B stride,swz]@0 (24576) + sc[44,192B,swz]@24576
//            (8448) + rels bf16[64][88]@33024 (11264)
// ---------------------------------------------------------------------------
template<bool WIDTH>
__global__ __launch_bounds__(256, 2)
void axial_kernel(const float* __restrict__ xsrc,
                  const ushort_t* __restrict__ phi_in, const ushort_t* __restrict__ plo_in,
                  ushort_t* __restrict__ phi_out, ushort_t* __restrict__ plo_out,
                  int sel,
                  const float* __restrict__ bnq,   // 4x512
                  const float* __restrict__ bns,   // 4x12
                  const float* __restrict__ bno,   // 4x512
                  const float* __restrict__ rel)   // 128x87
{
    __shared__ __align__(128) char smem[49152];

    const int blk = blockIdx.x;
    const int n   = blk / 44;
    const int col = blk - n * 44;
    const int b = n >> 2, i2 = (n >> 1) & 1, i4 = n & 1;
    const int t = threadIdx.x;
    const int wv = t >> 6, lane = t & 63;
    const int l15 = lane & 15, l16 = lane >> 4;

    // ---- phase 1: stage X split-bf16, swizzled [i=48][c=256] (rows 44..47 zero)
    if (!WIDTH) {
        const float* base = xsrc + ((b * 256) * 88 + i2 * 44) * 88 + i4 * 44 + col;
        for (int e = t; e < 6144; e += 256) {
            int i = e >> 7, cp = e & 127, c = cp * 2;
            unsigned packH = 0, packL = 0;
            if (i < 44) {
                float v0 = base[c * 7744 + i * 88];
                float v1 = base[(c + 1) * 7744 + i * 88];
                ushort_t h0 = f2bf_rn(v0), h1 = f2bf_rn(v1);
                ushort_t l0 = f2bf_rn(v0 - bf2f(h0)), l1 = f2bf_rn(v1 - bf2f(h1));
                packH = (unsigned)h0 | ((unsigned)h1 << 16);
                packL = (unsigned)l0 | ((unsigned)l1 << 16);
            }
            unsigned a = ((unsigned)(i * 512 + c * 2)) ^ (((unsigned)(i & 7)) << 4);
            *(unsigned*)(smem + a) = packH;
            *(unsigned*)(smem + 24576 + a) = packL;
        }
    } else {
        const ushort_t* ph = phi_in + (size_t)(n * 44 + col) * 44 * 256;
        const ushort_t* pl = plo_in + (size_t)(n * 44 + col) * 44 * 256;
        for (int e = t; e < 6144; e += 256) {
            int i = e >> 7, cp = e & 127;
            unsigned vH = 0, vL = 0;
            if (i < 44) {
                vH = *(const unsigned*)(ph + i * 256 + cp * 2);
                vL = *(const unsigned*)(pl + i * 256 + cp * 2);
            }
            unsigned a = ((unsigned)(i * 512 + cp * 4)) ^ (((unsigned)(i & 7)) << 4);
            *(unsigned*)(smem + a) = vH;
            *(unsigned*)(smem + 24576 + a) = vL;
        }
    }
    __syncthreads();

    // ---- phase 2: qkv GEMM via MFMA; wave g -> group g (M=128) in registers
    f32x4 acc[8][3];
    #pragma unroll
    for (int mf = 0; mf < 8; ++mf)
        #pragma unroll
        for (int nf = 0; nf < 3; ++nf) acc[mf][nf] = (f32x4)0.f;

    {
        const ushort_t* WH = g_qwhi[sel];
        const ushort_t* WL = g_qwlo[sel];
        for (int kt = 0; kt < 8; ++kt) {
            bf16x8 bh[3], bl[3];
            #pragma unroll
            for (int nf = 0; nf < 3; ++nf) {
                int i = nf * 16 + l15;
                unsigned a = ((unsigned)(i * 512 + kt * 64 + l16 * 16)) ^ (((unsigned)(i & 7)) << 4);
                bh[nf] = *(const bf16x8*)(smem + a);
                bl[nf] = *(const bf16x8*)(smem + 24576 + a);
            }
            #pragma unroll
            for (int mf = 0; mf < 8; ++mf) {
                int o = wv * 128 + mf * 16 + l15;
                size_t wb = ((size_t)(kt * 4 + l16) * 512 + o) * 8;
                bf16x8 ah = *(const bf16x8*)(WH + wb);
                bf16x8 al = *(const bf16x8*)(WL + wb);
                #pragma unroll
                for (int nf = 0; nf < 3; ++nf) {
                    acc[mf][nf] = __builtin_amdgcn_mfma_f32_16x16x32_bf16(ah, bh[nf], acc[mf][nf], 0, 0, 0);
                    acc[mf][nf] = __builtin_amdgcn_mfma_f32_16x16x32_bf16(al, bh[nf], acc[mf][nf], 0, 0, 0);
                    acc[mf][nf] = __builtin_amdgcn_mfma_f32_16x16x32_bf16(ah, bl[nf], acc[mf][nf], 0, 0, 0);
                }
            }
        }
    }
    __syncthreads();   // X now dead; LDS reused as qb/sc/rels

    // ---- stage q/k rel embeddings (rows 0..63) as bf16 [64][88]
    {
        ushort_t* rels = (ushort_t*)(smem + 33024);
        for (int e = t; e < 5568; e += 256) {
            int c = e / 87, d = e - c * 87;
            rels[c * 88 + d] = f2bf_rn(rel[c * 87 + d]);
        }
    }

    const ushort_t* rels = (const ushort_t*)(smem + 33024);

    for (int g = 0; g < 4; ++g) {
        // ---- wave g dumps its qkv (BN fused) into qb
        if (wv == g) {
            #pragma unroll
            for (int mf = 0; mf < 8; ++mf) {
                int r0 = mf * 16 + l16 * 4;
                int o0 = g * 128 + r0;
                #pragma unroll
                for (int r = 0; r < 4; ++r) {
                    int o = o0 + r;
                    float s = bnq[o] * rsqrtf(bnq[1536 + o] + EPSV);
                    float h = bnq[512 + o] - bnq[1024 + o] * s;
                    #pragma unroll
                    for (int nf = 0; nf < 3; ++nf) {
                        int i = nf * 16 + l15;
                        if (i < 44)
                            *(float*)(smem + swz192(r0 + r, i * 4)) = acc[mf][nf][r] * s + h;
                    }
                }
            }
        }
        __syncthreads();

        // ---- scores
        {
            const float sqk = bns[g]     * rsqrtf(bns[36 + g] + EPSV);
            const float sqr = bns[4 + g] * rsqrtf(bns[40 + g] + EPSV);
            const float skr = bns[8 + g] * rsqrtf(bns[44 + g] + EPSV);
            for (int e = t; e < 1936; e += 256) {
                int i = e / 44, j = e - i * 44;
                int dq = i - j + 43, dk = j - i + 43;
                float aqk = 0.f, aqr = 0.f, akr = 0.f;
                #pragma unroll 4
                for (int c = 0; c < 32; ++c) {
                    float qi = *(const float*)(smem + swz192(c, i * 4));
                    float kj = *(const float*)(smem + swz192(32 + c, j * 4));
                    aqk += qi * kj;
                    aqr += qi * bf2f(rels[c * 88 + dq]);
                    akr += kj * bf2f(rels[(32 + c) * 88 + dk]);
                }
                *(float*)(smem + 24576 + swz192(i, j * 4)) = sqk * aqk + 0.1f * (sqr * aqr + skr * akr);
            }
        }
        __syncthreads();

        // ---- softmax (wave per row)
        for (int i = wv; i < 44; i += 4) {
            float v = (lane < 44) ? *(const float*)(smem + 24576 + swz192(i, lane * 4)) : -INFINITY;
            float m = v;
            #pragma unroll
            for (int off = 32; off; off >>= 1) m = fmaxf(m, __shfl_xor(m, off));
            float ex = (lane < 44) ? __expf(v - m) : 0.f;
            float ssum = ex;
            #pragma unroll
            for (int off = 32; off; off >>= 1) ssum += __shfl_xor(ssum, off);
            if (lane < 44) *(float*)(smem + 24576 + swz192(i, lane * 4)) = ex / ssum;
        }
        __syncthreads();

        // ---- outputs: sv (LDS v) + sve (global rel rows 64+), bn_out, store
        for (int e = t; e < 2816; e += 256) {
            int c = e & 63, i = e >> 6;
            const float* relv = rel + (64 + c) * 87 + i + 43;
            float asv = 0.f, asve = 0.f;
            #pragma unroll
            for (int jj = 0; jj < 11; ++jj) {
                f32x4 s4 = *(const f32x4*)(smem + 24576 + swz192(i, jj * 16));
                f32x4 v4 = *(const f32x4*)(smem + swz192(64 + c, jj * 16));
                asv += s4[0] * v4[0] + s4[1] * v4[1] + s4[2] * v4[2] + s4[3] * v4[3];
                int j0 = jj * 4;
                asve += s4[0] * relv[-j0] + s4[1] * relv[-(j0 + 1)]
                      + s4[2] * relv[-(j0 + 2)] + s4[3] * relv[-(j0 + 3)];
            }
            int o0 = g * 128 + 2 * c;
            float s0 = bno[o0]     * rsqrtf(bno[1536 + o0] + EPSV);
            float h0 = bno[512 + o0] - bno[1024 + o0] * s0;
            float s1 = bno[o0 + 1] * rsqrtf(bno[1537 + o0] + EPSV);
            float h1 = bno[513 + o0] - bno[1025 + o0] * s1;
            float val = s0 * asv + h0 + s1 * (0.1f * asve) + h1;

            int cf = g * 64 + c;
            size_t idx;
            if (!WIDTH) {
                idx = ((size_t)(n * 44 + i) * 44 + col) * 256 + cf;
            } else {
                float r = xsrc[((size_t)(b * 256 + cf) * 88 + i2 * 44 + col) * 88 + i4 * 44 + i];
                val += r;
                idx = ((size_t)(n * 44 + col) * 44 + i) * 256 + cf;
            }
            ushort_t hi = f2bf_rn(val);
            ushort_t lo = f2bf_rn(val - bf2f(hi));
            phi_out[idx] = hi;
            plo_out[idx] = lo;
        }
        __syncthreads();   // protect qb before next group's dump
    }
}

// ---------------------------------------------------------------------------
// 3x3 SAME conv, split-bf16 MFMA implicit GEMM (validated round 2, unchanged)
// ---------------------------------------------------------------------------
__global__ __launch_bounds__(256)
void conv_kernel(const ushort_t* __restrict__ phi,
                 const ushort_t* __restrict__ plo,
                 const float* __restrict__ cb,
                 float* __restrict__ out)
{
    __shared__ __align__(16) ushort_t Xs2[2][4 * 50 * 32];

    const int yb = blockIdx.x, n = blockIdx.y;
    const int y0 = yb * 2;
    const int b = n >> 2, i2 = (n >> 1) & 1, i4 = n & 1;
    const int t = threadIdx.x;
    const int wv = t >> 6, lane = t & 63;
    const int l15 = lane & 15, l16 = lane >> 4;

    f32x4 acc[4][6];
    #pragma unroll
    for (int mf = 0; mf < 4; ++mf)
        #pragma unroll
        for (int nf = 0; nf < 6; ++nf) acc[mf][nf] = (f32x4)0.f;

    char* lds = (char*)&Xs2[0][0];

    for (int cit = 0; cit < 8; ++cit) {
        const int ci0 = cit * 32;
        __syncthreads();
        for (int m = t; m < 1600; m += 256) {
            int ci8 = m & 3;
            int rem = m >> 2;
            int col = rem % 50;
            int rr  = rem / 50;
            int arr = rr >> 2, rowidx = rr & 3;
            int gy = y0 - 1 + rowidx, gx = col - 1;
            u16x8 v = (u16x8)0;
            if (gy >= 0 && gy < 44 && gx >= 0 && gx < 44) {
                const ushort_t* src = (arr ? plo : phi)
                    + (size_t)((n * 44 + gy) * 44 + gx) * 256 + ci0 + ci8 * 8;
                v = *(const u16x8*)src;
            }
            unsigned int addr = (unsigned int)((rowidx * 50 + col) * 64 + ci8 * 16);
            addr ^= ((col & 7) << 4);
            *(u16x8*)(lds + arr * 12800 + addr) = v;
        }
        __syncthreads();

        for (int tap = 0; tap < 9; ++tap) {
            const int dy = tap / 3, dx = tap % 3;
            const size_t wb = ((size_t)((cit * 9 + tap) * 4 + l16) * 256 + wv * 64 + l15) * 8;
            const u16x8* wh = (const u16x8*)(g_cwhi + wb);
            const u16x8* wl = (const u16x8*)(g_cwlo + wb);
            bf16x8 ah[4], al[4];
            #pragma unroll
            for (int mf = 0; mf < 4; ++mf) {
                ah[mf] = (bf16x8)wh[mf * 16];
                al[mf] = (bf16x8)wl[mf * 16];
            }
            int colr = l15 + dx;
            unsigned int rbase = (unsigned int)((dy * 50 + colr) * 64 + l16 * 16);
            rbase ^= ((colr & 7) << 4);
            const char* hb = lds + rbase;

            #pragma unroll
            for (int nf = 0; nf < 6; ++nf) {
                const int ry = nf / 3, cbk = nf % 3;
                const int off = ry * 3200 + cbk * 1024;
                bf16x8 bh = *(const bf16x8*)(hb + off);
                bf16x8 bl = *(const bf16x8*)(hb + 12800 + off);
                #pragma unroll
                for (int mf = 0; mf < 4; ++mf) {
                    acc[mf][nf] = __builtin_amdgcn_mfma_f32_16x16x32_bf16(ah[mf], bh, acc[mf][nf], 0, 0, 0);
                    acc[mf][nf] = __builtin_amdgcn_mfma_f32_16x16x32_bf16(al[mf], bh, acc[mf][nf], 0, 0, 0);
                    acc[mf][nf] = __builtin_amdgcn_mfma_f32_16x16x32_bf16(ah[mf], bl, acc[mf][nf], 0, 0, 0);
                }
            }
        }
    }

    #pragma unroll
    for (int mf = 0; mf < 4; ++mf) {
        const int cobase = wv * 64 + mf * 16 + l16 * 4;
        float bias[4];
        #pragma unroll
        for (int r = 0; r < 4; ++r) bias[r] = cb[cobase + r];
        #pragma unroll
        for (int nf = 0; nf < 6; ++nf) {
            const int ry = nf / 3, cbk = nf % 3;
            const int x = cbk * 16 + l15;
            if (x < 44) {
                const int y = y0 + ry;
                #pragma unroll
                for (int r = 0; r < 4; ++r) {
                    const int co = cobase + r;
                    out[((size_t)(b * 256 + co) * 88 + i2 * 44 + y) * 88 + i4 * 44 + x]
                        = acc[mf][nf][r] + bias[r];
                }
            }
        }
    }
}

extern "C" void kernel_launch(void* const* d_in, const int* in_sizes, int n_in,
                              void* d_out, int out_size, void* d_ws, size_t ws_size,
                              hipStream_t stream)
{
    (void)in_sizes; (void)n_in; (void)out_size; (void)ws_size;

    const float* x        = (const float*)d_in[0];
    const float* h_qkv_w  = (const float*)d_in[1];
    const float* h_bn_qkv = (const float*)d_in[2];
    const float* h_bn_sim = (const float*)d_in[3];
    const float* h_bn_out = (const float*)d_in[4];
    const float* h_rel    = (const float*)d_in[5];
    const float* w_qkv_w  = (const float*)d_in[6];
    const float* w_bn_qkv = (const float*)d_in[7];
    const float* w_bn_sim = (const float*)d_in[8];
    const float* w_bn_out = (const float*)d_in[9];
    const float* w_rel    = (const float*)d_in[10];
    const float* conv_w   = (const float*)d_in[11];
    const float* conv_b   = (const float*)d_in[12];

    ushort_t* phi = (ushort_t*)d_ws;
    ushort_t* plo = phi + N_P;
    float* o = (float*)d_out;

    wsplit_conv<<<(N_CW + 255) / 256, 256, 0, stream>>>(conv_w);
    wsplit_qkv<<<(2 * N_QW + 255) / 256, 256, 0, stream>>>(h_qkv_w, w_qkv_w);

    axial_kernel<false><<<2816, 256, 0, stream>>>(x, nullptr, nullptr, phi, plo,
        0, h_bn_qkv, h_bn_sim, h_bn_out, h_rel);
    axial_kernel<true><<<2816, 256, 0, stream>>>(x, phi, plo, phi, plo,
        1, w_bn_qkv, w_bn_sim, w_bn_out, w_rel);
    conv_kernel<<<dim3(22, 64), 256, 0, stream>>>(phi, plo, conv_b, o);
}

// Round 4
// 2578.583 us; speedup vs baseline: 1.8461x; 1.8461x over previous
//
#include <hip/hip_runtime.h>
#include <math.h>

#define EPSV 1e-5f

typedef unsigned short u16t;
typedef unsigned int u32t;
typedef __attribute__((ext_vector_type(8))) short bf16x8;
typedef __attribute__((ext_vector_type(8))) unsigned short u16x8;
typedef __attribute__((ext_vector_type(4))) float f32x4;

#define N_P  31719424   // 64*256*44*44 elements of one p buffer
#define N_CW 589824     // conv weights
#define N_QW 131072     // qkv weights per axial

// fragment-ordered split-bf16 weights / bf16 rel tables (rewritten every launch)
__device__ __align__(16) u16t g_cwhi[N_CW], g_cwlo[N_CW];
__device__ __align__(16) u16t g_qwhi[2][N_QW], g_qwlo[2][N_QW];
__device__ __align__(16) u16t g_relq[2][3072];   // [d=96][c=32] bf16 of rel[c][d], rows 0..31
__device__ __align__(16) u16t g_relk[2][3072];   // [d=96][c=32] of rel[32+c][d]
__device__ __align__(16) u16t g_relv[2][6144];   // [c=64][d=96] of rel[64+c][d]

__device__ __forceinline__ u16t f2bf_rn(float f) {
    u32t u = __float_as_uint(f);
    u32t r = u + 0x7FFFu + ((u >> 16) & 1u);
    return (u16t)(r >> 16);
}
__device__ __forceinline__ float bf2f(u16t h) {
    return __uint_as_float(((u32t)h) << 16);
}

// ---------------------------------------------------------------------------
__global__ __launch_bounds__(256)
void wsplit_conv(const float* __restrict__ cw)
{
    int idx = blockIdx.x * 256 + threadIdx.x;
    if (idx >= N_CW) return;
    int tap = idx % 9;
    int rem = idx / 9;
    int ci = rem & 255, co = rem >> 8;
    float w = cw[idx];
    u16t hi = f2bf_rn(w);
    u16t lo = f2bf_rn(w - bf2f(hi));
    int cit = ci >> 5, ci5 = ci & 31, ci8 = ci5 >> 3, e = ci5 & 7;
    int didx = (((cit * 9 + tap) * 4 + ci8) * 256 + co) * 8 + e;
    g_cwhi[didx] = hi;
    g_cwlo[didx] = lo;
}

__global__ __launch_bounds__(256)
void wsplit_qkv(const float* __restrict__ wh_, const float* __restrict__ ww_)
{
    int idx = blockIdx.x * 256 + threadIdx.x;
    if (idx >= 2 * N_QW) return;
    int sel = idx >> 17;
    int id  = idx & (N_QW - 1);
    float w = (sel ? ww_ : wh_)[id];
    u16t hi = f2bf_rn(w);
    u16t lo = f2bf_rn(w - bf2f(hi));
    int o = id >> 8, c = id & 255;
    int kt = c >> 5, ci8 = (c >> 3) & 3, e = c & 7;
    int didx = ((kt * 4 + ci8) * 512 + o) * 8 + e;
    g_qwhi[sel][didx] = hi;
    g_qwlo[sel][didx] = lo;
}

// rel tables, bf16, d-padded to 96 with zeros
__global__ __launch_bounds__(256)
void wsplit_rel(const float* __restrict__ rh, const float* __restrict__ rw)
{
    int idx = blockIdx.x * 256 + threadIdx.x;
    if (idx >= 24576) return;
    int sel = idx >= 12288;
    int id  = idx - sel * 12288;
    const float* rel = sel ? rw : rh;
    if (id < 3072) {
        int d = id >> 5, c = id & 31;
        g_relq[sel][id] = (d < 87) ? f2bf_rn(rel[c * 87 + d]) : (u16t)0;
    } else if (id < 6144) {
        int j = id - 3072;
        int d = j >> 5, c = j & 31;
        g_relk[sel][j] = (d < 87) ? f2bf_rn(rel[(32 + c) * 87 + d]) : (u16t)0;
    } else {
        int j = id - 6144;
        int c = j / 96, d = j - c * 96;
        g_relv[sel][j] = (d < 87) ? f2bf_rn(rel[(64 + c) * 87 + d]) : (u16t)0;
    }
}

// ---------------------------------------------------------------------------
// Axial attention, full-MFMA. One block per (column, group). 256 thr.
// LDS (62720 B static, 2 blocks/CU), regions time-shared:
//  P0/P1 : Xh @0 (24576), Xl @24576 (24576)   [i=48][c=256] swz ^((i&7)<<4)
//  after : Qh @0, Ql @3072, Kh @6144, Kl @9216        [48][32] bf16 swz
//          Vh @12288, Vl @20480                       [64][64] bf16 swz
//          Ph @28672, Pl @34816 (KR bf16 [48][96] swz lives here first)
//          Rb @40960 (R bf16 [48][96] swz, later S2)
//          sc/bounce @50176: f32, stride 49 words, 64 rows (12544 B)
// ---------------------------------------------------------------------------
#define OFF_XL 24576
#define OFF_QH 0
#define OFF_QL 3072
#define OFF_KH 6144
#define OFF_KL 9216
#define OFF_VH 12288
#define OFF_VL 20480
#define OFF_PH 28672
#define OFF_PL 34816
#define OFF_KR 28672
#define OFF_RB 40960
#define OFF_SC 50176

template<int WIDTH>
__global__ __launch_bounds__(256, 2)
void axial_kernel(const float* __restrict__ xsrc,
                  const u16t* __restrict__ pin_h, const u16t* __restrict__ pin_l,
                  u16t* __restrict__ pout_h, u16t* __restrict__ pout_l,
                  int sel,
                  const float* __restrict__ bnq,
                  const float* __restrict__ bns,
                  const float* __restrict__ bno)
{
    __shared__ __align__(128) char smem[62720];

    const int blk = blockIdx.x;
    const int g   = blockIdx.y;
    const int n   = blk / 44;
    const int col = blk - n * 44;
    const int b = n >> 2, i2 = (n >> 1) & 1, i4 = n & 1;
    const int t = threadIdx.x;
    const int wv = t >> 6, lane = t & 63;
    const int l15 = lane & 15, l16 = lane >> 4;

    // ---- P0: stage X split-bf16 [i=48][c=256], rows 44..47 zero ----
    if (!WIDTH) {
        const float* base = xsrc + ((b * 256) * 88 + i2 * 44) * 88 + i4 * 44 + col;
        for (int e = t; e < 6144; e += 256) {
            int i = e >> 7, cp = e & 127, c = cp * 2;
            u32t packH = 0, packL = 0;
            if (i < 44) {
                float v0 = base[c * 7744 + i * 88];
                float v1 = base[(c + 1) * 7744 + i * 88];
                u16t h0 = f2bf_rn(v0), h1 = f2bf_rn(v1);
                u16t l0 = f2bf_rn(v0 - bf2f(h0)), l1 = f2bf_rn(v1 - bf2f(h1));
                packH = (u32t)h0 | ((u32t)h1 << 16);
                packL = (u32t)l0 | ((u32t)l1 << 16);
            }
            u32t a = ((u32t)(i * 512 + c * 2)) ^ (((u32t)(i & 7)) << 4);
            *(u32t*)(smem + a) = packH;
            *(u32t*)(smem + OFF_XL + a) = packL;
        }
    } else {
        const u16t* ph = pin_h + (size_t)(n * 44 + col) * 44 * 256;
        const u16t* pl = pin_l + (size_t)(n * 44 + col) * 44 * 256;
        for (int e = t; e < 6144; e += 256) {
            int i = e >> 7, cp = e & 127;
            u32t vH = 0, vL = 0;
            if (i < 44) {
                vH = *(const u32t*)(ph + i * 256 + cp * 2);
                vL = *(const u32t*)(pl + i * 256 + cp * 2);
            }
            u32t a = ((u32t)(i * 512 + cp * 4)) ^ (((u32t)(i & 7)) << 4);
            *(u32t*)(smem + a) = vH;
            *(u32t*)(smem + OFF_XL + a) = vL;
        }
    }
    __syncthreads();

    // ---- P1: qkv GEMM (this group's 128 rows), wave -> 32 rows ----
    f32x4 acc[2][3];
    #pragma unroll
    for (int mf = 0; mf < 2; ++mf)
        #pragma unroll
        for (int nf = 0; nf < 3; ++nf) acc[mf][nf] = (f32x4)0.f;
    {
        const u16t* WH = g_qwhi[sel];
        const u16t* WL = g_qwlo[sel];
        for (int kt = 0; kt < 8; ++kt) {
            bf16x8 bh[3], bl[3];
            #pragma unroll
            for (int nf = 0; nf < 3; ++nf) {
                int i = nf * 16 + l15;
                u32t a = ((u32t)(i * 512 + kt * 64 + l16 * 16)) ^ (((u32t)(i & 7)) << 4);
                bh[nf] = *(const bf16x8*)(smem + a);
                bl[nf] = *(const bf16x8*)(smem + OFF_XL + a);
            }
            #pragma unroll
            for (int mf = 0; mf < 2; ++mf) {
                int o = g * 128 + wv * 32 + mf * 16 + l15;
                size_t wb = ((size_t)(kt * 4 + l16) * 512 + o) * 8;
                bf16x8 ah = *(const bf16x8*)(WH + wb);
                bf16x8 al = *(const bf16x8*)(WL + wb);
                #pragma unroll
                for (int nf = 0; nf < 3; ++nf) {
                    acc[mf][nf] = __builtin_amdgcn_mfma_f32_16x16x32_bf16(ah, bh[nf], acc[mf][nf], 0, 0, 0);
                    acc[mf][nf] = __builtin_amdgcn_mfma_f32_16x16x32_bf16(al, bh[nf], acc[mf][nf], 0, 0, 0);
                    acc[mf][nf] = __builtin_amdgcn_mfma_f32_16x16x32_bf16(ah, bl[nf], acc[mf][nf], 0, 0, 0);
                }
            }
        }
    }
    __syncthreads();   // X dead

    // ---- P2: zero V pad cols (j=44..63) + dump q/k/v with BN, split-bf16 ----
    for (int e = t; e < 1280; e += 256) {
        int arr = e & 1, q = e >> 1;
        int c = q / 10, k = q - c * 10;
        u32t ad = ((u32t)(c * 128 + 88 + k * 4)) ^ (((u32t)(c & 7)) << 4);
        *(u32t*)(smem + (arr ? OFF_VL : OFF_VH) + ad) = 0;
    }
    #pragma unroll
    for (int mf = 0; mf < 2; ++mf) {
        #pragma unroll
        for (int r = 0; r < 4; ++r) {
            int ol = wv * 32 + mf * 16 + l16 * 4 + r;
            int o  = g * 128 + ol;
            float s = bnq[o] * rsqrtf(bnq[1536 + o] + EPSV);
            float h = bnq[512 + o] - bnq[1024 + o] * s;
            #pragma unroll
            for (int nf = 0; nf < 3; ++nf) {
                int i = nf * 16 + l15;
                float val = acc[mf][nf][r] * s + h;
                u16t hi = f2bf_rn(val);
                u16t lo = f2bf_rn(val - bf2f(hi));
                if (ol < 32) {
                    u32t a = ((u32t)(i * 64 + ol * 2)) ^ (((u32t)(i & 7)) << 4);
                    *(u16t*)(smem + OFF_QH + a) = hi;
                    *(u16t*)(smem + OFF_QL + a) = lo;
                } else if (ol < 64) {
                    int c = ol - 32;
                    u32t a = ((u32t)(i * 64 + c * 2)) ^ (((u32t)(i & 7)) << 4);
                    *(u16t*)(smem + OFF_KH + a) = hi;
                    *(u16t*)(smem + OFF_KL + a) = lo;
                } else if (i < 44) {
                    int c = ol - 64;
                    u32t a = ((u32t)(c * 128 + i * 2)) ^ (((u32t)(c & 7)) << 4);
                    *(u16t*)(smem + OFF_VH + a) = hi;
                    *(u16t*)(smem + OFF_VL + a) = lo;
                }
            }
        }
    }
    __syncthreads();

    // ---- P3a: qk (split 3-term) -> sc ; R = Q.rel_q -> Rb ; KR = K.rel_k -> PH region ----
    for (int f = wv; f < 9; f += 4) {
        int mf = f / 3, nf = f % 3;
        int ia = mf * 16 + l15;
        u32t aq = ((u32t)(ia * 64 + l16 * 16)) ^ (((u32t)(ia & 7)) << 4);
        bf16x8 qh = *(const bf16x8*)(smem + OFF_QH + aq);
        bf16x8 ql = *(const bf16x8*)(smem + OFF_QL + aq);
        int jb = nf * 16 + l15;
        u32t ak = ((u32t)(jb * 64 + l16 * 16)) ^ (((u32t)(jb & 7)) << 4);
        bf16x8 kh = *(const bf16x8*)(smem + OFF_KH + ak);
        bf16x8 kl = *(const bf16x8*)(smem + OFF_KL + ak);
        f32x4 d = (f32x4)0.f;
        d = __builtin_amdgcn_mfma_f32_16x16x32_bf16(qh, kh, d, 0, 0, 0);
        d = __builtin_amdgcn_mfma_f32_16x16x32_bf16(ql, kh, d, 0, 0, 0);
        d = __builtin_amdgcn_mfma_f32_16x16x32_bf16(qh, kl, d, 0, 0, 0);
        #pragma unroll
        for (int r = 0; r < 4; ++r) {
            int i = mf * 16 + l16 * 4 + r;
            *(float*)(smem + OFF_SC + (i * 49 + nf * 16 + l15) * 4) = d[r];
        }
    }
    for (int f = wv; f < 18; f += 4) {
        int mf = f / 6, nf = f % 6;
        int ia = mf * 16 + l15;
        u32t aq = ((u32t)(ia * 64 + l16 * 16)) ^ (((u32t)(ia & 7)) << 4);
        bf16x8 qh = *(const bf16x8*)(smem + OFF_QH + aq);
        bf16x8 rb = *(const bf16x8*)(&g_relq[sel][(nf * 16 + l15) * 32 + l16 * 8]);
        f32x4 d = (f32x4)0.f;
        d = __builtin_amdgcn_mfma_f32_16x16x32_bf16(qh, rb, d, 0, 0, 0);
        #pragma unroll
        for (int r = 0; r < 4; ++r) {
            int i = mf * 16 + l16 * 4 + r;
            u32t a = ((u32t)(i * 192 + (nf * 16 + l15) * 2)) ^ (((u32t)(i & 7)) << 4);
            *(u16t*)(smem + OFF_RB + a) = f2bf_rn(d[r]);
        }
    }
    for (int f = wv; f < 18; f += 4) {
        int mf = f / 6, nf = f % 6;
        int ja = mf * 16 + l15;
        u32t ak = ((u32t)(ja * 64 + l16 * 16)) ^ (((u32t)(ja & 7)) << 4);
        bf16x8 kh = *(const bf16x8*)(smem + OFF_KH + ak);
        bf16x8 rb = *(const bf16x8*)(&g_relk[sel][(nf * 16 + l15) * 32 + l16 * 8]);
        f32x4 d = (f32x4)0.f;
        d = __builtin_amdgcn_mfma_f32_16x16x32_bf16(kh, rb, d, 0, 0, 0);
        #pragma unroll
        for (int r = 0; r < 4; ++r) {
            int j = mf * 16 + l16 * 4 + r;
            u32t a = ((u32t)(j * 192 + (nf * 16 + l15) * 2)) ^ (((u32t)(j & 7)) << 4);
            *(u16t*)(smem + OFF_KR + a) = f2bf_rn(d[r]);
        }
    }
    __syncthreads();

    // ---- P3b: score assembly with gathered qr/kr ----
    {
        const float sqk = bns[g]     * rsqrtf(bns[36 + g] + EPSV);
        const float sqr = bns[4 + g] * rsqrtf(bns[40 + g] + EPSV);
        const float skr = bns[8 + g] * rsqrtf(bns[44 + g] + EPSV);
        for (int e = t; e < 1936; e += 256) {
            int i = e / 44, j = e - i * 44;
            int dq = i - j + 43, dk = j - i + 43;
            float scv = *(const float*)(smem + OFF_SC + (i * 49 + j) * 4);
            u16t rq = *(const u16t*)(smem + OFF_RB + (((u32t)(i * 192 + dq * 2)) ^ (((u32t)(i & 7)) << 4)));
            u16t rk = *(const u16t*)(smem + OFF_KR + (((u32t)(j * 192 + dk * 2)) ^ (((u32t)(j & 7)) << 4)));
            *(float*)(smem + OFF_SC + (i * 49 + j) * 4) =
                sqk * scv + 0.1f * (sqr * bf2f(rq) + skr * bf2f(rk));
        }
    }
    __syncthreads();

    // ---- P3c: softmax, wave per row ----
    for (int i = wv; i < 44; i += 4) {
        float v = (lane < 44) ? *(const float*)(smem + OFF_SC + (i * 49 + lane) * 4) : -INFINITY;
        float m = v;
        #pragma unroll
        for (int off = 32; off; off >>= 1) m = fmaxf(m, __shfl_xor(m, off));
        float ex = (lane < 44) ? __expf(v - m) : 0.f;
        float ssum = ex;
        #pragma unroll
        for (int off = 32; off; off >>= 1) ssum += __shfl_xor(ssum, off);
        if (lane < 44) *(float*)(smem + OFF_SC + (i * 49 + lane) * 4) = ex / ssum;
    }
    __syncthreads();

    // ---- P3d: P split-bf16 [48][64] (zero-padded) + S2 gather [48][96] bf16 ----
    for (int e = t; e < 3072; e += 256) {
        int i = e >> 6, j = e & 63;
        float v = (i < 44 && j < 44) ? *(const float*)(smem + OFF_SC + (i * 49 + j) * 4) : 0.f;
        u16t hi = f2bf_rn(v);
        u16t lo = f2bf_rn(v - bf2f(hi));
        u32t a = ((u32t)(i * 128 + j * 2)) ^ (((u32t)(i & 7)) << 4);
        *(u16t*)(smem + OFF_PH + a) = hi;
        *(u16t*)(smem + OFF_PL + a) = lo;
    }
    for (int e = t; e < 4608; e += 256) {
        int i = e / 96, d = e - i * 96;
        int j = i - d + 43;
        u16t v = 0;
        if (i < 44 && j >= 0 && j < 44)
            v = f2bf_rn(*(const float*)(smem + OFF_SC + (i * 49 + j) * 4));
        u32t a = ((u32t)(i * 192 + d * 2)) ^ (((u32t)(i & 7)) << 4);
        *(u16t*)(smem + OFF_RB + a) = v;
    }
    __syncthreads();

    // ---- P3e: SV (split 3-term) + SVE (bf16) -> regs; bn_out; bounce f32 [c][i] ----
    {
        f32x4 svf[3], svef[3];
        int fi = 0;
        for (int f = wv; f < 12; f += 4, ++fi) {
            int mf = f / 3, nf = f % 3;
            f32x4 dsv = (f32x4)0.f, dsve = (f32x4)0.f;
            #pragma unroll
            for (int kt = 0; kt < 2; ++kt) {
                int ca = mf * 16 + l15;
                u32t av = ((u32t)(ca * 128 + kt * 64 + l16 * 16)) ^ (((u32t)(ca & 7)) << 4);
                bf16x8 vh = *(const bf16x8*)(smem + OFF_VH + av);
                bf16x8 vl = *(const bf16x8*)(smem + OFF_VL + av);
                int ib = nf * 16 + l15;
                u32t ap = ((u32t)(ib * 128 + kt * 64 + l16 * 16)) ^ (((u32t)(ib & 7)) << 4);
                bf16x8 ph = *(const bf16x8*)(smem + OFF_PH + ap);
                bf16x8 pl = *(const bf16x8*)(smem + OFF_PL + ap);
                dsv = __builtin_amdgcn_mfma_f32_16x16x32_bf16(vh, ph, dsv, 0, 0, 0);
                dsv = __builtin_amdgcn_mfma_f32_16x16x32_bf16(vl, ph, dsv, 0, 0, 0);
                dsv = __builtin_amdgcn_mfma_f32_16x16x32_bf16(vh, pl, dsv, 0, 0, 0);
            }
            #pragma unroll
            for (int kt = 0; kt < 3; ++kt) {
                int ca = mf * 16 + l15;
                bf16x8 ar = *(const bf16x8*)(&g_relv[sel][ca * 96 + kt * 32 + l16 * 8]);
                int ib = nf * 16 + l15;
                u32t as = ((u32t)(ib * 192 + kt * 64 + l16 * 16)) ^ (((u32t)(ib & 7)) << 4);
                bf16x8 s2 = *(const bf16x8*)(smem + OFF_RB + as);
                dsve = __builtin_amdgcn_mfma_f32_16x16x32_bf16(ar, s2, dsve, 0, 0, 0);
            }
            svf[fi] = dsv; svef[fi] = dsve;
        }
        fi = 0;
        for (int f = wv; f < 12; f += 4, ++fi) {
            int mf = f / 3, nf = f % 3;
            #pragma unroll
            for (int r = 0; r < 4; ++r) {
                int c = mf * 16 + l16 * 4 + r;
                int o0 = g * 128 + 2 * c;
                float s0 = bno[o0]     * rsqrtf(bno[1536 + o0] + EPSV);
                float h0 = bno[512 + o0] - bno[1024 + o0] * s0;
                float s1 = bno[o0 + 1] * rsqrtf(bno[1537 + o0] + EPSV);
                float h1 = bno[513 + o0] - bno[1025 + o0] * s1;
                int i = nf * 16 + l15;
                float val = s0 * svf[fi][r] + h0 + s1 * (0.1f * svef[fi][r]) + h1;
                *(float*)(smem + OFF_SC + (c * 49 + i) * 4) = val;
            }
        }
    }
    __syncthreads();

    // ---- P3f: coalesced split-bf16 store (+ residual for WIDTH pass) ----
    for (int e = t; e < 2816; e += 256) {
        int c = e & 63, i = e >> 6;
        float val = *(const float*)(smem + OFF_SC + (c * 49 + i) * 4);
        int cf = g * 64 + c;
        size_t idx;
        if (!WIDTH) {
            idx = ((size_t)(n * 44 + i) * 44 + col) * 256 + cf;
        } else {
            float r = xsrc[((size_t)(b * 256 + cf) * 88 + i2 * 44 + col) * 88 + i4 * 44 + i];
            val += r;
            idx = ((size_t)(n * 44 + col) * 44 + i) * 256 + cf;
        }
        u16t hi = f2bf_rn(val);
        u16t lo = f2bf_rn(val - bf2f(hi));
        pout_h[idx] = hi;
        pout_l[idx] = lo;
    }
}

// ---------------------------------------------------------------------------
// 3x3 SAME conv, split-bf16 MFMA implicit GEMM (validated round 2, unchanged)
// ---------------------------------------------------------------------------
__global__ __launch_bounds__(256)
void conv_kernel(const u16t* __restrict__ phi,
                 const u16t* __restrict__ plo,
                 const float* __restrict__ cb,
                 float* __restrict__ out)
{
    __shared__ __align__(16) u16t Xs2[2][4 * 50 * 32];

    const int yb = blockIdx.x, n = blockIdx.y;
    const int y0 = yb * 2;
    const int b = n >> 2, i2 = (n >> 1) & 1, i4 = n & 1;
    const int t = threadIdx.x;
    const int wv = t >> 6, lane = t & 63;
    const int l15 = lane & 15, l16 = lane >> 4;

    f32x4 acc[4][6];
    #pragma unroll
    for (int mf = 0; mf < 4; ++mf)
        #pragma unroll
        for (int nf = 0; nf < 6; ++nf) acc[mf][nf] = (f32x4)0.f;

    char* lds = (char*)&Xs2[0][0];

    for (int cit = 0; cit < 8; ++cit) {
        const int ci0 = cit * 32;
        __syncthreads();
        for (int m = t; m < 1600; m += 256) {
            int ci8 = m & 3;
            int rem = m >> 2;
            int colm = rem % 50;
            int rr  = rem / 50;
            int arr = rr >> 2, rowidx = rr & 3;
            int gy = y0 - 1 + rowidx, gx = colm - 1;
            u16x8 v = (u16x8)0;
            if (gy >= 0 && gy < 44 && gx >= 0 && gx < 44) {
                const u16t* src = (arr ? plo : phi)
                    + (size_t)((n * 44 + gy) * 44 + gx) * 256 + ci0 + ci8 * 8;
                v = *(const u16x8*)src;
            }
            u32t addr = (u32t)((rowidx * 50 + colm) * 64 + ci8 * 16);
            addr ^= ((colm & 7) << 4);
            *(u16x8*)(lds + arr * 12800 + addr) = v;
        }
        __syncthreads();

        for (int tap = 0; tap < 9; ++tap) {
            const int dy = tap / 3, dx = tap % 3;
            const size_t wb = ((size_t)((cit * 9 + tap) * 4 + l16) * 256 + wv * 64 + l15) * 8;
            const u16x8* wh = (const u16x8*)(g_cwhi + wb);
            const u16x8* wl = (const u16x8*)(g_cwlo + wb);
            bf16x8 ah[4], al[4];
            #pragma unroll
            for (int mf = 0; mf < 4; ++mf) {
                ah[mf] = (bf16x8)wh[mf * 16];
                al[mf] = (bf16x8)wl[mf * 16];
            }
            int colr = l15 + dx;
            u32t rbase = (u32t)((dy * 50 + colr) * 64 + l16 * 16);
            rbase ^= ((colr & 7) << 4);
            const char* hb = lds + rbase;

            #pragma unroll
            for (int nf = 0; nf < 6; ++nf) {
                const int ry = nf / 3, cbk = nf % 3;
                const int off = ry * 3200 + cbk * 1024;
                bf16x8 bh = *(const bf16x8*)(hb + off);
                bf16x8 bl = *(const bf16x8*)(hb + 12800 + off);
                #pragma unroll
                for (int mf = 0; mf < 4; ++mf) {
                    acc[mf][nf] = __builtin_amdgcn_mfma_f32_16x16x32_bf16(ah[mf], bh, acc[mf][nf], 0, 0, 0);
                    acc[mf][nf] = __builtin_amdgcn_mfma_f32_16x16x32_bf16(al[mf], bh, acc[mf][nf], 0, 0, 0);
                    acc[mf][nf] = __builtin_amdgcn_mfma_f32_16x16x32_bf16(ah[mf], bl, acc[mf][nf], 0, 0, 0);
                }
            }
        }
    }

    #pragma unroll
    for (int mf = 0; mf < 4; ++mf) {
        const int cobase = wv * 64 + mf * 16 + l16 * 4;
        float bias[4];
        #pragma unroll
        for (int r = 0; r < 4; ++r) bias[r] = cb[cobase + r];
        #pragma unroll
        for (int nf = 0; nf < 6; ++nf) {
            const int ry = nf / 3, cbk = nf % 3;
            const int x = cbk * 16 + l15;
            if (x < 44) {
                const int y = y0 + ry;
                #pragma unroll
                for (int r = 0; r < 4; ++r) {
                    const int co = cobase + r;
                    out[((size_t)(b * 256 + co) * 88 + i2 * 44 + y) * 88 + i4 * 44 + x]
                        = acc[mf][nf][r] + bias[r];
                }
            }
        }
    }
}

extern "C" void kernel_launch(void* const* d_in, const int* in_sizes, int n_in,
                              void* d_out, int out_size, void* d_ws, size_t ws_size,
                              hipStream_t stream)
{
    (void)in_sizes; (void)n_in; (void)out_size; (void)ws_size;

    const float* x        = (const float*)d_in[0];
    const float* h_qkv_w  = (const float*)d_in[1];
    const float* h_bn_qkv = (const float*)d_in[2];
    const float* h_bn_sim = (const float*)d_in[3];
    const float* h_bn_out = (const float*)d_in[4];
    const float* h_rel    = (const float*)d_in[5];
    const float* w_qkv_w  = (const float*)d_in[6];
    const float* w_bn_qkv = (const float*)d_in[7];
    const float* w_bn_sim = (const float*)d_in[8];
    const float* w_bn_out = (const float*)d_in[9];
    const float* w_rel    = (const float*)d_in[10];
    const float* conv_w   = (const float*)d_in[11];
    const float* conv_b   = (const float*)d_in[12];

    u16t* p1h = (u16t*)d_ws;
    u16t* p1l = p1h + N_P;
    u16t* p2h = p1l + N_P;
    u16t* p2l = p2h + N_P;
    float* o  = (float*)d_out;

    wsplit_conv<<<(N_CW + 255) / 256, 256, 0, stream>>>(conv_w);
    wsplit_qkv<<<(2 * N_QW + 255) / 256, 256, 0, stream>>>(h_qkv_w, w_qkv_w);
    wsplit_rel<<<96, 256, 0, stream>>>(h_rel, w_rel);

    axial_kernel<0><<<dim3(2816, 4), 256, 0, stream>>>(x, nullptr, nullptr, p1h, p1l,
        0, h_bn_qkv, h_bn_sim, h_bn_out);
    axial_kernel<1><<<dim3(2816, 4), 256, 0, stream>>>(x, p1h, p1l, p2h, p2l,
        1, w_bn_qkv, w_bn_sim, w_bn_out);
    conv_kernel<<<dim3(22, 64), 256, 0, stream>>>(p2h, p2l, conv_b, o);
}

// Round 6
// 1780.185 us; speedup vs baseline: 2.6741x; 1.4485x over previous
//
#include <hip/hip_runtime.h>
#include <math.h>

#define EPSV 1e-5f

typedef unsigned short u16t;
typedef unsigned int u32t;
typedef __attribute__((ext_vector_type(8))) short bf16x8;
typedef __attribute__((ext_vector_type(8))) unsigned short u16x8;
typedef __attribute__((ext_vector_type(4))) float f32x4;

#define N_P  31719424   // 64*44*44*256 elements (xt / p layout)
#define N_CW 589824     // conv weights
#define N_QW 131072     // qkv weights per axial

// fragment-ordered split-bf16 weights / bf16 rel tables (rewritten every launch)
__device__ __align__(16) u16t g_cwhi[N_CW], g_cwlo[N_CW];
__device__ __align__(16) u16t g_qwhi[2][N_QW], g_qwlo[2][N_QW];
__device__ __align__(16) u16t g_relq[2][3072];   // [d=96][c=32] bf16 of rel[c][d], rows 0..31
__device__ __align__(16) u16t g_relk[2][3072];   // [d=96][c=32] of rel[32+c][d]
__device__ __align__(16) u16t g_relv[2][6144];   // [c=64][d=96] of rel[64+c][d]

__device__ __forceinline__ u16t f2bf_rn(float f) {
    u32t u = __float_as_uint(f);
    u32t r = u + 0x7FFFu + ((u >> 16) & 1u);
    return (u16t)(r >> 16);
}
__device__ __forceinline__ float bf2f(u16t h) {
    return __uint_as_float(((u32t)h) << 16);
}

// ---------------------------------------------------------------------------
// Patchify + transpose x -> channels-last split-bf16 xt[n][y][x][c].
// Block: (cg, yy, b); reads 64c x 88x slab coalesced, LDS transpose,
// writes 128B-contiguous c-runs.
// ---------------------------------------------------------------------------
__global__ __launch_bounds__(256)
void transpose_x(const float* __restrict__ x,
                 u16t* __restrict__ xth, u16t* __restrict__ xtl)
{
    __shared__ u16t th[64][90];
    __shared__ u16t tl[64][90];
    const int cg = blockIdx.x, yy = blockIdx.y, b = blockIdx.z;
    const int t = threadIdx.x;
    const float* src = x + ((size_t)(b * 256 + cg * 64) * 88 + yy) * 88;
    for (int e = t; e < 5632; e += 256) {
        int c = e / 88, xx = e - c * 88;
        float v = src[(size_t)c * 7744 + xx];
        u16t hi = f2bf_rn(v);
        u16t lo = f2bf_rn(v - bf2f(hi));
        th[c][xx] = hi;
        tl[c][xx] = lo;
    }
    __syncthreads();
    const int i2 = (yy >= 44);
    const int yl = yy - 44 * i2;
    for (int u = t; u < 5632; u += 256) {
        int xx = u >> 6, c = u & 63;
        int i4 = (xx >= 44);
        int xl = xx - 44 * i4;
        int n = b * 4 + i2 * 2 + i4;
        size_t idx = ((size_t)(n * 44 + yl) * 44 + xl) * 256 + cg * 64 + c;
        xth[idx] = th[c][xx];
        xtl[idx] = tl[c][xx];
    }
}

// ---------------------------------------------------------------------------
__global__ __launch_bounds__(256)
void wsplit_conv(const float* __restrict__ cw)
{
    int idx = blockIdx.x * 256 + threadIdx.x;
    if (idx >= N_CW) return;
    int tap = idx % 9;
    int rem = idx / 9;
    int ci = rem & 255, co = rem >> 8;
    float w = cw[idx];
    u16t hi = f2bf_rn(w);
    u16t lo = f2bf_rn(w - bf2f(hi));
    int cit = ci >> 5, ci5 = ci & 31, ci8 = ci5 >> 3, e = ci5 & 7;
    int didx = (((cit * 9 + tap) * 4 + ci8) * 256 + co) * 8 + e;
    g_cwhi[didx] = hi;
    g_cwlo[didx] = lo;
}

__global__ __launch_bounds__(256)
void wsplit_qkv(const float* __restrict__ wh_, const float* __restrict__ ww_)
{
    int idx = blockIdx.x * 256 + threadIdx.x;
    if (idx >= 2 * N_QW) return;
    int sel = idx >> 17;
    int id  = idx & (N_QW - 1);
    float w = (sel ? ww_ : wh_)[id];
    u16t hi = f2bf_rn(w);
    u16t lo = f2bf_rn(w - bf2f(hi));
    int o = id >> 8, c = id & 255;
    int kt = c >> 5, ci8 = (c >> 3) & 3, e = c & 7;
    int didx = ((kt * 4 + ci8) * 512 + o) * 8 + e;
    g_qwhi[sel][didx] = hi;
    g_qwlo[sel][didx] = lo;
}

__global__ __launch_bounds__(256)
void wsplit_rel(const float* __restrict__ rh, const float* __restrict__ rw)
{
    int idx = blockIdx.x * 256 + threadIdx.x;
    if (idx >= 24576) return;
    int sel = idx >= 12288;
    int id  = idx - sel * 12288;
    const float* rel = sel ? rw : rh;
    if (id < 3072) {
        int d = id >> 5, c = id & 31;
        g_relq[sel][id] = (d < 87) ? f2bf_rn(rel[c * 87 + d]) : (u16t)0;
    } else if (id < 6144) {
        int j = id - 3072;
        int d = j >> 5, c = j & 31;
        g_relk[sel][j] = (d < 87) ? f2bf_rn(rel[(32 + c) * 87 + d]) : (u16t)0;
    } else {
        int j = id - 6144;
        int c = j / 96, d = j - c * 96;
        g_relv[sel][j] = (d < 87) ? f2bf_rn(rel[(64 + c) * 87 + d]) : (u16t)0;
    }
}

// ---------------------------------------------------------------------------
// Axial attention, full-MFMA, merged: one block per column (n,col), 256 thr,
// all 4 groups. qkv GEMM rows interleaved: o = (mf*4+wv)*16 + l15, so each
// wave holds frags mf=2g (q/k) and 2g+1 (v) of every group -> balanced dump.
// LDS 62720 B (2 blocks/CU), regions identical to round 4, X overlaid.
// ---------------------------------------------------------------------------
#define OFF_XL 24576
#define OFF_QH 0
#define OFF_QL 3072
#define OFF_KH 6144
#define OFF_KL 9216
#define OFF_VH 12288
#define OFF_VL 20480
#define OFF_PH 28672
#define OFF_PL 34816
#define OFF_KR 28672
#define OFF_RB 40960
#define OFF_SC 50176

template<int WIDTH>
__global__ __launch_bounds__(256, 2)
void axial_kernel(const u16t* __restrict__ sh, const u16t* __restrict__ sl,
                  const u16t* __restrict__ resh, const u16t* __restrict__ resl,
                  u16t* __restrict__ outh, u16t* __restrict__ outl,
                  int sel,
                  const float* __restrict__ bnq,
                  const float* __restrict__ bns,
                  const float* __restrict__ bno)
{
    __shared__ __align__(128) char smem[62720];

    const int blk = blockIdx.x;
    const int n   = blk / 44;
    const int col = blk - n * 44;
    const int t = threadIdx.x;
    const int wv = t >> 6, lane = t & 63;
    const int l15 = lane & 15, l16 = lane >> 4;

    // ---- P0: stage X split-bf16 [i=48][c=256] swizzled (rows 44..47 zero) ----
    if (!WIDTH) {
        // column = fixed x=col, i = y; xt[n][i][col][c]
        for (int e = t; e < 6144; e += 256) {
            int i = e >> 7, cp = e & 127;
            u32t vH = 0, vL = 0;
            if (i < 44) {
                size_t s0 = ((size_t)(n * 44 + i) * 44 + col) * 256 + cp * 2;
                vH = *(const u32t*)(sh + s0);
                vL = *(const u32t*)(sl + s0);
            }
            u32t a = ((u32t)(i * 512 + cp * 4)) ^ (((u32t)(i & 7)) << 4);
            *(u32t*)(smem + a) = vH;
            *(u32t*)(smem + OFF_XL + a) = vL;
        }
    } else {
        // column = fixed y=col, i = x; p[n][col][i][c]  (contiguous)
        const u16t* ph = sh + (size_t)(n * 44 + col) * 44 * 256;
        const u16t* pl = sl + (size_t)(n * 44 + col) * 44 * 256;
        for (int e = t; e < 6144; e += 256) {
            int i = e >> 7, cp = e & 127;
            u32t vH = 0, vL = 0;
            if (i < 44) {
                vH = *(const u32t*)(ph + i * 256 + cp * 2);
                vL = *(const u32t*)(pl + i * 256 + cp * 2);
            }
            u32t a = ((u32t)(i * 512 + cp * 4)) ^ (((u32t)(i & 7)) << 4);
            *(u32t*)(smem + a) = vH;
            *(u32t*)(smem + OFF_XL + a) = vL;
        }
    }
    __syncthreads();

    // ---- P1: qkv GEMM, all 512 rows; acc[8][3], o = (mf*4+wv)*16 + l15 ----
    f32x4 acc[8][3];
    #pragma unroll
    for (int mf = 0; mf < 8; ++mf)
        #pragma unroll
        for (int nf = 0; nf < 3; ++nf) acc[mf][nf] = (f32x4)0.f;
    {
        const u16t* WH = g_qwhi[sel];
        const u16t* WL = g_qwlo[sel];
        for (int kt = 0; kt < 8; ++kt) {
            bf16x8 bh[3], bl[3];
            #pragma unroll
            for (int nf = 0; nf < 3; ++nf) {
                int i = nf * 16 + l15;
                u32t a = ((u32t)(i * 512 + kt * 64 + l16 * 16)) ^ (((u32t)(i & 7)) << 4);
                bh[nf] = *(const bf16x8*)(smem + a);
                bl[nf] = *(const bf16x8*)(smem + OFF_XL + a);
            }
            #pragma unroll
            for (int mf = 0; mf < 8; ++mf) {
                int o = (mf * 4 + wv) * 16 + l15;
                size_t wb = ((size_t)(kt * 4 + l16) * 512 + o) * 8;
                bf16x8 ah = *(const bf16x8*)(WH + wb);
                bf16x8 al = *(const bf16x8*)(WL + wb);
                #pragma unroll
                for (int nf = 0; nf < 3; ++nf) {
                    acc[mf][nf] = __builtin_amdgcn_mfma_f32_16x16x32_bf16(ah, bh[nf], acc[mf][nf], 0, 0, 0);
                    acc[mf][nf] = __builtin_amdgcn_mfma_f32_16x16x32_bf16(al, bh[nf], acc[mf][nf], 0, 0, 0);
                    acc[mf][nf] = __builtin_amdgcn_mfma_f32_16x16x32_bf16(ah, bl[nf], acc[mf][nf], 0, 0, 0);
                }
            }
        }
    }
    __syncthreads();   // X dead; LDS becomes group buffers

    // ---- zero V pad cols (j=44..63) once; dumps never touch them ----
    for (int e = t; e < 1280; e += 256) {
        int arr = e & 1, q = e >> 1;
        int c = q / 10, k = q - c * 10;
        u32t ad = ((u32t)(c * 128 + 88 + k * 4)) ^ (((u32t)(c & 7)) << 4);
        *(u32t*)(smem + (arr ? OFF_VL : OFF_VH) + ad) = 0;
    }

    for (int g = 0; g < 4; ++g) {
        // ---- select this group's fragments with static indices ----
        f32x4 fq[3], fv[3];
        #pragma unroll
        for (int nf = 0; nf < 3; ++nf) { fq[nf] = acc[0][nf]; fv[nf] = acc[1][nf]; }
        #pragma unroll
        for (int m = 1; m < 4; ++m) {
            if (g == m) {
                #pragma unroll
                for (int nf = 0; nf < 3; ++nf) { fq[nf] = acc[2 * m][nf]; fv[nf] = acc[2 * m + 1][nf]; }
            }
        }

        // ---- P2: dump q/k/v with BN (all 4 waves, 2 frags each) ----
        #pragma unroll
        for (int r = 0; r < 4; ++r) {
            int ol = wv * 16 + l16 * 4 + r;       // 0..63
            {   // frag mf=2g -> q (ol<32) / k (ol>=32)
                int o = g * 128 + ol;
                float s = bnq[o] * rsqrtf(bnq[1536 + o] + EPSV);
                float h = bnq[512 + o] - bnq[1024 + o] * s;
                #pragma unroll
                for (int nf = 0; nf < 3; ++nf) {
                    int i = nf * 16 + l15;
                    float val = fq[nf][r] * s + h;
                    u16t hi = f2bf_rn(val);
                    u16t lo = f2bf_rn(val - bf2f(hi));
                    if (ol < 32) {
                        u32t a = ((u32t)(i * 64 + ol * 2)) ^ (((u32t)(i & 7)) << 4);
                        *(u16t*)(smem + OFF_QH + a) = hi;
                        *(u16t*)(smem + OFF_QL + a) = lo;
                    } else {
                        int c = ol - 32;
                        u32t a = ((u32t)(i * 64 + c * 2)) ^ (((u32t)(i & 7)) << 4);
                        *(u16t*)(smem + OFF_KH + a) = hi;
                        *(u16t*)(smem + OFF_KL + a) = lo;
                    }
                }
            }
            {   // frag mf=2g+1 -> v channel c = ol
                int c = ol;
                int o = g * 128 + 64 + c;
                float s = bnq[o] * rsqrtf(bnq[1536 + o] + EPSV);
                float h = bnq[512 + o] - bnq[1024 + o] * s;
                #pragma unroll
                for (int nf = 0; nf < 3; ++nf) {
                    int i = nf * 16 + l15;
                    if (i < 44) {
                        float val = fv[nf][r] * s + h;
                        u16t hi = f2bf_rn(val);
                        u16t lo = f2bf_rn(val - bf2f(hi));
                        u32t a = ((u32t)(c * 128 + i * 2)) ^ (((u32t)(c & 7)) << 4);
                        *(u16t*)(smem + OFF_VH + a) = hi;
                        *(u16t*)(smem + OFF_VL + a) = lo;
                    }
                }
            }
        }
        __syncthreads();

        // ---- P3a: qk -> sc ; R = Q.rel_q -> RB ; KR = K.rel_k -> P region ----
        for (int f = wv; f < 9; f += 4) {
            int mf = f / 3, nf = f % 3;
            int ia = mf * 16 + l15;
            u32t aq = ((u32t)(ia * 64 + l16 * 16)) ^ (((u32t)(ia & 7)) << 4);
            bf16x8 qh = *(const bf16x8*)(smem + OFF_QH + aq);
            bf16x8 ql = *(const bf16x8*)(smem + OFF_QL + aq);
            int jb = nf * 16 + l15;
            u32t ak = ((u32t)(jb * 64 + l16 * 16)) ^ (((u32t)(jb & 7)) << 4);
            bf16x8 kh = *(const bf16x8*)(smem + OFF_KH + ak);
            bf16x8 kl = *(const bf16x8*)(smem + OFF_KL + ak);
            f32x4 d = (f32x4)0.f;
            d = __builtin_amdgcn_mfma_f32_16x16x32_bf16(qh, kh, d, 0, 0, 0);
            d = __builtin_amdgcn_mfma_f32_16x16x32_bf16(ql, kh, d, 0, 0, 0);
            d = __builtin_amdgcn_mfma_f32_16x16x32_bf16(qh, kl, d, 0, 0, 0);
            #pragma unroll
            for (int r = 0; r < 4; ++r) {
                int i = mf * 16 + l16 * 4 + r;
                *(float*)(smem + OFF_SC + (i * 49 + nf * 16 + l15) * 4) = d[r];
            }
        }
        for (int f = wv; f < 18; f += 4) {
            int mf = f / 6, nf = f % 6;
            int ia = mf * 16 + l15;
            u32t aq = ((u32t)(ia * 64 + l16 * 16)) ^ (((u32t)(ia & 7)) << 4);
            bf16x8 qh = *(const bf16x8*)(smem + OFF_QH + aq);
            bf16x8 rb = *(const bf16x8*)(&g_relq[sel][(nf * 16 + l15) * 32 + l16 * 8]);
            f32x4 d = (f32x4)0.f;
            d = __builtin_amdgcn_mfma_f32_16x16x32_bf16(qh, rb, d, 0, 0, 0);
            #pragma unroll
            for (int r = 0; r < 4; ++r) {
                int i = mf * 16 + l16 * 4 + r;
                u32t a = ((u32t)(i * 192 + (nf * 16 + l15) * 2)) ^ (((u32t)(i & 7)) << 4);
                *(u16t*)(smem + OFF_RB + a) = f2bf_rn(d[r]);
            }
        }
        for (int f = wv; f < 18; f += 4) {
            int mf = f / 6, nf = f % 6;
            int ja = mf * 16 + l15;
            u32t ak = ((u32t)(ja * 64 + l16 * 16)) ^ (((u32t)(ja & 7)) << 4);
            bf16x8 kh = *(const bf16x8*)(smem + OFF_KH + ak);
            bf16x8 rb = *(const bf16x8*)(&g_relk[sel][(nf * 16 + l15) * 32 + l16 * 8]);
            f32x4 d = (f32x4)0.f;
            d = __builtin_amdgcn_mfma_f32_16x16x32_bf16(kh, rb, d, 0, 0, 0);
            #pragma unroll
            for (int r = 0; r < 4; ++r) {
                int j = mf * 16 + l16 * 4 + r;
                u32t a = ((u32t)(j * 192 + (nf * 16 + l15) * 2)) ^ (((u32t)(j & 7)) << 4);
                *(u16t*)(smem + OFF_KR + a) = f2bf_rn(d[r]);
            }
        }
        __syncthreads();

        // ---- P3b: score assembly ----
        {
            const float sqk = bns[g]     * rsqrtf(bns[36 + g] + EPSV);
            const float sqr = bns[4 + g] * rsqrtf(bns[40 + g] + EPSV);
            const float skr = bns[8 + g] * rsqrtf(bns[44 + g] + EPSV);
            for (int e = t; e < 1936; e += 256) {
                int i = e / 44, j = e - i * 44;
                int dq = i - j + 43, dk = j - i + 43;
                float scv = *(const float*)(smem + OFF_SC + (i * 49 + j) * 4);
                u16t rq = *(const u16t*)(smem + OFF_RB + (((u32t)(i * 192 + dq * 2)) ^ (((u32t)(i & 7)) << 4)));
                u16t rk = *(const u16t*)(smem + OFF_KR + (((u32t)(j * 192 + dk * 2)) ^ (((u32t)(j & 7)) << 4)));
                *(float*)(smem + OFF_SC + (i * 49 + j) * 4) =
                    sqk * scv + 0.1f * (sqr * bf2f(rq) + skr * bf2f(rk));
            }
        }
        __syncthreads();

        // ---- P3c: softmax, wave per row ----
        for (int i = wv; i < 44; i += 4) {
            float v = (lane < 44) ? *(const float*)(smem + OFF_SC + (i * 49 + lane) * 4) : -INFINITY;
            float m = v;
            #pragma unroll
            for (int off = 32; off; off >>= 1) m = fmaxf(m, __shfl_xor(m, off));
            float ex = (lane < 44) ? __expf(v - m) : 0.f;
            float ssum = ex;
            #pragma unroll
            for (int off = 32; off; off >>= 1) ssum += __shfl_xor(ssum, off);
            if (lane < 44) *(float*)(smem + OFF_SC + (i * 49 + lane) * 4) = ex / ssum;
        }
        __syncthreads();

        // ---- P3d: P split-bf16 [48][64] + S2 gather [48][96] bf16 ----
        for (int e = t; e < 3072; e += 256) {
            int i = e >> 6, j = e & 63;
            float v = (i < 44 && j < 44) ? *(const float*)(smem + OFF_SC + (i * 49 + j) * 4) : 0.f;
            u16t hi = f2bf_rn(v);
            u16t lo = f2bf_rn(v - bf2f(hi));
            u32t a = ((u32t)(i * 128 + j * 2)) ^ (((u32t)(i & 7)) << 4);
            *(u16t*)(smem + OFF_PH + a) = hi;
            *(u16t*)(smem + OFF_PL + a) = lo;
        }
        for (int e = t; e < 4608; e += 256) {
            int i = e / 96, d = e - i * 96;
            int j = i - d + 43;
            u16t v = 0;
            if (i < 44 && j >= 0 && j < 44)
                v = f2bf_rn(*(const float*)(smem + OFF_SC + (i * 49 + j) * 4));
            u32t a = ((u32t)(i * 192 + d * 2)) ^ (((u32t)(i & 7)) << 4);
            *(u16t*)(smem + OFF_RB + a) = v;
        }
        __syncthreads();

        // ---- P3e: SV + SVE -> regs, bn_out, bounce f32 [c][i] into SC ----
        {
            f32x4 svf[3], svef[3];
            int fi = 0;
            for (int f = wv; f < 12; f += 4, ++fi) {
                int mf = f / 3, nf = f % 3;
                f32x4 dsv = (f32x4)0.f, dsve = (f32x4)0.f;
                #pragma unroll
                for (int kt = 0; kt < 2; ++kt) {
                    int ca = mf * 16 + l15;
                    u32t av = ((u32t)(ca * 128 + kt * 64 + l16 * 16)) ^ (((u32t)(ca & 7)) << 4);
                    bf16x8 vh = *(const bf16x8*)(smem + OFF_VH + av);
                    bf16x8 vl = *(const bf16x8*)(smem + OFF_VL + av);
                    int ib = nf * 16 + l15;
                    u32t ap = ((u32t)(ib * 128 + kt * 64 + l16 * 16)) ^ (((u32t)(ib & 7)) << 4);
                    bf16x8 ph = *(const bf16x8*)(smem + OFF_PH + ap);
                    bf16x8 pl = *(const bf16x8*)(smem + OFF_PL + ap);
                    dsv = __builtin_amdgcn_mfma_f32_16x16x32_bf16(vh, ph, dsv, 0, 0, 0);
                    dsv = __builtin_amdgcn_mfma_f32_16x16x32_bf16(vl, ph, dsv, 0, 0, 0);
                    dsv = __builtin_amdgcn_mfma_f32_16x16x32_bf16(vh, pl, dsv, 0, 0, 0);
                }
                #pragma unroll
                for (int kt = 0; kt < 3; ++kt) {
                    int ca = mf * 16 + l15;
                    bf16x8 ar = *(const bf16x8*)(&g_relv[sel][ca * 96 + kt * 32 + l16 * 8]);
                    int ib = nf * 16 + l15;
                    u32t as = ((u32t)(ib * 192 + kt * 64 + l16 * 16)) ^ (((u32t)(ib & 7)) << 4);
                    bf16x8 s2 = *(const bf16x8*)(smem + OFF_RB + as);
                    dsve = __builtin_amdgcn_mfma_f32_16x16x32_bf16(ar, s2, dsve, 0, 0, 0);
                }
                svf[fi] = dsv; svef[fi] = dsve;
            }
            __syncthreads();   // SC score reads done; safe to overwrite as bounce
            fi = 0;
            for (int f = wv; f < 12; f += 4, ++fi) {
                int mf = f / 3, nf = f % 3;
                #pragma unroll
                for (int r = 0; r < 4; ++r) {
                    int c = mf * 16 + l16 * 4 + r;
                    int o0 = g * 128 + 2 * c;
                    float s0 = bno[o0]     * rsqrtf(bno[1536 + o0] + EPSV);
                    float h0 = bno[512 + o0] - bno[1024 + o0] * s0;
                    float s1 = bno[o0 + 1] * rsqrtf(bno[1537 + o0] + EPSV);
                    float h1 = bno[513 + o0] - bno[1025 + o0] * s1;
                    int i = nf * 16 + l15;
                    float val = s0 * svf[fi][r] + h0 + s1 * (0.1f * svef[fi][r]) + h1;
                    *(float*)(smem + OFF_SC + (c * 49 + i) * 4) = val;
                }
            }
        }
        __syncthreads();

        // ---- P3f: coalesced split-bf16 store (+ residual for WIDTH pass) ----
        for (int e = t; e < 2816; e += 256) {
            int c = e & 63, i = e >> 6;
            float val = *(const float*)(smem + OFF_SC + (c * 49 + i) * 4);
            int cf = g * 64 + c;
            size_t idx;
            if (!WIDTH) {
                idx = ((size_t)(n * 44 + i) * 44 + col) * 256 + cf;
            } else {
                idx = ((size_t)(n * 44 + col) * 44 + i) * 256 + cf;
                val += bf2f(resh[idx]) + bf2f(resl[idx]);
            }
            u16t hi = f2bf_rn(val);
            u16t lo = f2bf_rn(val - bf2f(hi));
            outh[idx] = hi;
            outl[idx] = lo;
        }
        __syncthreads();   // SC/Q/K/V reused next group
    }
}

// ---------------------------------------------------------------------------
// 3x3 SAME conv, split-bf16 MFMA implicit GEMM (validated round 2, unchanged)
// ---------------------------------------------------------------------------
__global__ __launch_bounds__(256)
void conv_kernel(const u16t* __restrict__ phi,
                 const u16t* __restrict__ plo,
                 const float* __restrict__ cb,
                 float* __restrict__ out)
{
    __shared__ __align__(16) u16t Xs2[2][4 * 50 * 32];

    const int yb = blockIdx.x, n = blockIdx.y;
    const int y0 = yb * 2;
    const int b = n >> 2, i2 = (n >> 1) & 1, i4 = n & 1;
    const int t = threadIdx.x;
    const int wv = t >> 6, lane = t & 63;
    const int l15 = lane & 15, l16 = lane >> 4;

    f32x4 acc[4][6];
    #pragma unroll
    for (int mf = 0; mf < 4; ++mf)
        #pragma unroll
        for (int nf = 0; nf < 6; ++nf) acc[mf][nf] = (f32x4)0.f;

    char* lds = (char*)&Xs2[0][0];

    for (int cit = 0; cit < 8; ++cit) {
        const int ci0 = cit * 32;
        __syncthreads();
        for (int m = t; m < 1600; m += 256) {
            int ci8 = m & 3;
            int rem = m >> 2;
            int colm = rem % 50;
            int rr  = rem / 50;
            int arr = rr >> 2, rowidx = rr & 3;
            int gy = y0 - 1 + rowidx, gx = colm - 1;
            u16x8 v = (u16x8)0;
            if (gy >= 0 && gy < 44 && gx >= 0 && gx < 44) {
                const u16t* src = (arr ? plo : phi)
                    + (size_t)((n * 44 + gy) * 44 + gx) * 256 + ci0 + ci8 * 8;
                v = *(const u16x8*)src;
            }
            u32t addr = (u32t)((rowidx * 50 + colm) * 64 + ci8 * 16);
            addr ^= ((colm & 7) << 4);
            *(u16x8*)(lds + arr * 12800 + addr) = v;
        }
        __syncthreads();

        for (int tap = 0; tap < 9; ++tap) {
            const int dy = tap / 3, dx = tap % 3;
            const size_t wb = ((size_t)((cit * 9 + tap) * 4 + l16) * 256 + wv * 64 + l15) * 8;
            const u16x8* wh = (const u16x8*)(g_cwhi + wb);
            const u16x8* wl = (const u16x8*)(g_cwlo + wb);
            bf16x8 ah[4], al[4];
            #pragma unroll
            for (int mf = 0; mf < 4; ++mf) {
                ah[mf] = (bf16x8)wh[mf * 16];
                al[mf] = (bf16x8)wl[mf * 16];
            }
            int colr = l15 + dx;
            u32t rbase = (u32t)((dy * 50 + colr) * 64 + l16 * 16);
            rbase ^= ((colr & 7) << 4);
            const char* hb = lds + rbase;

            #pragma unroll
            for (int nf = 0; nf < 6; ++nf) {
                const int ry = nf / 3, cbk = nf % 3;
                const int off = ry * 3200 + cbk * 1024;
                bf16x8 bh = *(const bf16x8*)(hb + off);
                bf16x8 bl = *(const bf16x8*)(hb + 12800 + off);
                #pragma unroll
                for (int mf = 0; mf < 4; ++mf) {
                    acc[mf][nf] = __builtin_amdgcn_mfma_f32_16x16x32_bf16(ah[mf], bh, acc[mf][nf], 0, 0, 0);
                    acc[mf][nf] = __builtin_amdgcn_mfma_f32_16x16x32_bf16(al[mf], bh, acc[mf][nf], 0, 0, 0);
                    acc[mf][nf] = __builtin_amdgcn_mfma_f32_16x16x32_bf16(ah[mf], bl, acc[mf][nf], 0, 0, 0);
                }
            }
        }
    }

    #pragma unroll
    for (int mf = 0; mf < 4; ++mf) {
        const int cobase = wv * 64 + mf * 16 + l16 * 4;
        float bias[4];
        #pragma unroll
        for (int r = 0; r < 4; ++r) bias[r] = cb[cobase + r];
        #pragma unroll
        for (int nf = 0; nf < 6; ++nf) {
            const int ry = nf / 3, cbk = nf % 3;
            const int x = cbk * 16 + l15;
            if (x < 44) {
                const int y = y0 + ry;
                #pragma unroll
                for (int r = 0; r < 4; ++r) {
                    const int co = cobase + r;
                    out[((size_t)(b * 256 + co) * 88 + i2 * 44 + y) * 88 + i4 * 44 + x]
                        = acc[mf][nf][r] + bias[r];
                }
            }
        }
    }
}

extern "C" void kernel_launch(void* const* d_in, const int* in_sizes, int n_in,
                              void* d_out, int out_size, void* d_ws, size_t ws_size,
                              hipStream_t stream)
{
    (void)in_sizes; (void)n_in; (void)out_size; (void)ws_size;

    const float* x        = (const float*)d_in[0];
    const float* h_qkv_w  = (const float*)d_in[1];
    const float* h_bn_qkv = (const float*)d_in[2];
    const float* h_bn_sim = (const float*)d_in[3];
    const float* h_bn_out = (const float*)d_in[4];
    const float* h_rel    = (const float*)d_in[5];
    const float* w_qkv_w  = (const float*)d_in[6];
    const float* w_bn_qkv = (const float*)d_in[7];
    const float* w_bn_sim = (const float*)d_in[8];
    const float* w_bn_out = (const float*)d_in[9];
    const float* w_rel    = (const float*)d_in[10];
    const float* conv_w   = (const float*)d_in[11];
    const float* conv_b   = (const float*)d_in[12];

    u16t* xth = (u16t*)d_ws;
    u16t* xtl = xth + N_P;
    u16t* p1h = xtl + N_P;
    u16t* p1l = p1h + N_P;
    float* o  = (float*)d_out;

    transpose_x<<<dim3(4, 88, 16), 256, 0, stream>>>(x, xth, xtl);
    wsplit_conv<<<(N_CW + 255) / 256, 256, 0, stream>>>(conv_w);
    wsplit_qkv<<<(2 * N_QW + 255) / 256, 256, 0, stream>>>(h_qkv_w, w_qkv_w);
    wsplit_rel<<<96, 256, 0, stream>>>(h_rel, w_rel);

    // height-axis: xt -> p1
    axial_kernel<0><<<2816, 256, 0, stream>>>(xth, xtl, nullptr, nullptr, p1h, p1l,
        0, h_bn_qkv, h_bn_sim, h_bn_out);
    // width-axis: p1 -> p1 (in place, block-owns-slice), residual from xt
    axial_kernel<1><<<2816, 256, 0, stream>>>(p1h, p1l, xth, xtl, p1h, p1l,
        1, w_bn_qkv, w_bn_sim, w_bn_out);
    conv_kernel<<<dim3(22, 64), 256, 0, stream>>>(p1h, p1l, conv_b, o);
}